// Round 5
// baseline (211.165 us; speedup 1.0000x reference)
//
#include <hip/hip_runtime.h>
#include <float.h>

#define B_  8
#define C_  16
#define N_  (B_*C_)
#define F_  256
#define H_  112
#define W_  112
#define HW_ (H_*W_)
#define NB_ 3

#define RB_STRIDE 40      // rowbits stride per cell (ulongs); bh <= 37
#define NPACK 14          // packed bin rows: max bin len = 13 (szy=35 -> bin1 = 24-11),
                          // +1 headroom. Clamped duplicates idempotent under max (proven r3/r4).

#define LPITCH 116        // LDS plane pitch in floats (112+4: spreads bank phase 80B/row)
#define FPB    8          // feature planes streamed serially per block
#define NCHUNK 49         // 1KB chunks per plane: 112*112 floats = 3136 float4 = 49*64

// ws layout: bb[N_][16] ints at offset 0 (8 KB), rowbits[N_][RB_STRIDE] ulong at +8192.
// bb per cell: y0,y1,x0,x1, ys[3], ye[3], xs[3], xe[3]

__global__ __launch_bounds__(256) void bbox_kernel(const int4* __restrict__ mask4,
                                                   int* __restrict__ bb,
                                                   unsigned long long* __restrict__ rowbits) {
    int n = blockIdx.x, t = threadIdx.x;
    const int4* m = mask4 + (size_t)n * (HW_ / 4);
    int ymin = 1 << 20, ymax = -1, xmin = 1 << 20, xmax = -1;
    // W_/4 = 28 int4 per row; an int4 never straddles rows.
    for (int i = t; i < HW_ / 4; i += 256) {
        int4 v = m[i];
        int y = i / 28;
        int xb = (i - y * 28) * 4;
        if (v.x | v.y | v.z | v.w) { ymin = min(ymin, y); ymax = max(ymax, y); }
        if (v.x) { xmin = min(xmin, xb);     xmax = max(xmax, xb);     }
        if (v.y) { xmin = min(xmin, xb + 1); xmax = max(xmax, xb + 1); }
        if (v.z) { xmin = min(xmin, xb + 2); xmax = max(xmax, xb + 2); }
        if (v.w) { xmin = min(xmin, xb + 3); xmax = max(xmax, xb + 3); }
    }
    #pragma unroll
    for (int off = 32; off; off >>= 1) {
        ymin = min(ymin, __shfl_xor(ymin, off));
        ymax = max(ymax, __shfl_xor(ymax, off));
        xmin = min(xmin, __shfl_xor(xmin, off));
        xmax = max(xmax, __shfl_xor(xmax, off));
    }
    __shared__ int red[4][4];
    __shared__ int sb[3];                 // y0, bh, x0a for phase 2
    int wave = t >> 6;
    if ((t & 63) == 0) {
        red[wave][0] = ymin; red[wave][1] = ymax;
        red[wave][2] = xmin; red[wave][3] = xmax;
    }
    __syncthreads();
    if (t == 0) {
        for (int w = 1; w < 4; ++w) {
            ymin = min(ymin, red[w][0]); ymax = max(ymax, red[w][1]);
            xmin = min(xmin, red[w][2]); xmax = max(xmax, red[w][3]);
        }
        int y0 = ymin, y1 = ymax + 1, x0 = xmin, x1 = xmax + 1;
        int* o = bb + n * 16;
        o[0] = y0; o[1] = y1; o[2] = x0; o[3] = x1;
        int szy = y1 - y0, szx = x1 - x0;
        for (int i = 0; i < NB_; ++i) {
            o[4+i]  = y0 + (i*szy)/NB_;
            o[7+i]  = y0 + ((i+1)*szy + NB_-1)/NB_;
            o[10+i] = x0 + (i*szx)/NB_;
            o[13+i] = x0 + ((i+1)*szx + NB_-1)/NB_;
        }
        sb[0] = y0; sb[1] = szy; sb[2] = x0 & ~3;
    }
    __syncthreads();
    // Phase 2: one 64-bit bitmap per bbox row via ballot. Bit l = mask at col x0a+l.
    // Cols >= W wrap into the next row of the SAME cell; garbage bits sit at
    // cols >= W > x1 and are excluded by the pool epilogue's x-bin lim.
    {
        int y0 = sb[0], bh = sb[1], x0a = sb[2];
        int lane = t & 63;
        const int* mrow = (const int*)mask4 + (size_t)n * HW_ + x0a + lane;
        for (int dy = wave; dy < bh; dy += 4) {
            int v = mrow[(size_t)(y0 + dy) * W_];
            unsigned long long bits = __ballot(v != 0);
            if (lane == 0) rowbits[n * RB_STRIDE + dy] = bits;
        }
    }
}

// STREAMING pool: grid = 256 blocks (8 b x 32 f-chunks), 512 threads = 8 waves,
// 1 block/CU (104 KB LDS). Each block streams FPB=8 full feature planes (50 KB,
// contiguous, coalesced -> HBM in fill-kernel regime) through a double-buffered
// LDS, pipelined: issue loads p+1 -> compute p from LDS -> ds_write p+1 -> barrier.
// Per wave: 2 cells; bb/rowbits/mynib/lims hoisted to ONCE per block (amortized
// over 8 features). Compute per (cell,plane) = proven r3/r4 machinery reading
// LDS instead of global: 14 clamped bin rows, mynib nibbles, epilogue lim +
// 16-lane shuffle reduce. LPITCH=116 phase-shifts rows by 80B to spread banks.
__global__ __launch_bounds__(512, 2) void pool_kernel(
        const float* __restrict__ feat,
        const unsigned long long* __restrict__ rowbits,
        const int* __restrict__ bb, float* __restrict__ out) {
    __shared__ float buf[2][112 * LPITCH];   // 103,936 B

    int bid = blockIdx.x;
    int b  = bid >> 5;                // batch
    int f0 = (bid & 31) * FPB;        // first feature of this block

    int tid = threadIdx.x;
    int lane = tid & 63, w = tid >> 6;
    int xq = lane & 15, rg = lane >> 4;
    int bi = min(rg, 2);              // rg3 duplicates bin2: idempotent under max

    // ---- per-wave cell prologue (2 cells per wave), overlaps plane-0 latency ----
    int ysb[2], yeb1[2], lcol[2], xgc[2];
    int xs[2][3], xe[2][3];
    unsigned long long mynib[2];
    #pragma unroll
    for (int cc = 0; cc < 2; ++cc) {
        int n = b * C_ + 2 * w + cc;
        const int* o = bb + n * 16;
        int y0 = o[0], x0 = o[2];
        int bw = o[3] - x0;
        int x0a = x0 & ~3;
        int wbw = (x0 - x0a) + bw;
        int xq4 = (4 * xq < wbw) ? 4 * xq : 0;   // clamp far lanes; epilogue-excluded
        ysb[cc]  = o[4 + bi];
        yeb1[cc] = o[7 + bi] - 1;
        lcol[cc] = x0a + xq4;                    // LDS float col (16B aligned)
        xgc[cc]  = x0a + 4 * xq;                 // UNclamped for lim
        #pragma unroll
        for (int j = 0; j < 3; ++j) { xs[cc][j] = o[10 + j]; xe[cc][j] = o[13 + j]; }
        unsigned long long nib = 0;
        const unsigned long long* rbp = rowbits + n * RB_STRIDE;
        #pragma unroll
        for (int u = 0; u < NPACK; ++u) {
            int dy = min(ysb[cc] + u, yeb1[cc]) - y0;
            nib |= ((rbp[dy] >> (4 * xq)) & 0xFull) << (4 * u);
        }
        mynib[cc] = nib;
    }

    // ---- staging: 49 1KB chunks/plane round-robin over 8 waves (6-7 each) ----
    const float* fbase = feat + (size_t)(b * F_ + f0) * HW_;
    float4 v[7];
    #define ISSUE(p)                                                        \
        { const float* fp = fbase + (size_t)(p) * HW_;                      \
          _Pragma("unroll")                                                 \
          for (int k = 0; k < 7; ++k) {                                     \
              int ch = k * 8 + w;                                           \
              if (ch < NCHUNK) v[k] = *(const float4*)(fp + 4*(ch*64+lane)); } }
    #define WRLDS(pb)                                                       \
        { float* dst = buf[pb];                                             \
          _Pragma("unroll")                                                 \
          for (int k = 0; k < 7; ++k) {                                     \
              int ch = k * 8 + w;                                           \
              if (ch < NCHUNK) {                                            \
                  int i = ch * 64 + lane;                                   \
                  int r = i / 28, c4 = i - 28 * r;                          \
                  *(float4*)(dst + r * LPITCH + 4 * c4) = v[k]; } } }

    ISSUE(0);
    WRLDS(0);                          // compiler inserts graded vmcnt per use
    __syncthreads();

    for (int p = 0; p < FPB; ++p) {
        if (p + 1 < FPB) ISSUE(p + 1); // loads stay in flight under compute (T14)

        const float* bp = buf[p & 1];
        #pragma unroll
        for (int cc = 0; cc < 2; ++cc) {
            float4 cr[NPACK];
            #pragma unroll
            for (int u = 0; u < NPACK; ++u) {
                int row = min(ysb[cc] + u, yeb1[cc]);      // absolute row
                cr[u] = *(const float4*)(bp + row * LPITCH + lcol[cc]);
            }
            float a0 = -FLT_MAX, a1 = -FLT_MAX, a2 = -FLT_MAX, a3 = -FLT_MAX;
            #pragma unroll
            for (int u = 0; u < NPACK; ++u) {
                unsigned int nib = (unsigned int)(mynib[cc] >> (4 * u)) & 0xFu;
                a0 = fmaxf(a0, (nib & 1u) ? cr[u].x : 0.f);
                a1 = fmaxf(a1, (nib & 2u) ? cr[u].y : 0.f);
                a2 = fmaxf(a2, (nib & 4u) ? cr[u].z : 0.f);
                a3 = fmaxf(a3, (nib & 8u) ? cr[u].w : 0.f);
            }
            float part[3];
            #pragma unroll
            for (int j = 0; j < 3; ++j) {
                int xx = xgc[cc];
                float r;
                r = fminf(a0, (xx     >= xs[cc][j] && xx     < xe[cc][j]) ? FLT_MAX : -FLT_MAX);
                r = fmaxf(r, fminf(a1, (xx + 1 >= xs[cc][j] && xx + 1 < xe[cc][j]) ? FLT_MAX : -FLT_MAX));
                r = fmaxf(r, fminf(a2, (xx + 2 >= xs[cc][j] && xx + 2 < xe[cc][j]) ? FLT_MAX : -FLT_MAX));
                r = fmaxf(r, fminf(a3, (xx + 3 >= xs[cc][j] && xx + 3 < xe[cc][j]) ? FLT_MAX : -FLT_MAX));
                part[j] = r;
            }
            #pragma unroll
            for (int off = 1; off <= 8; off <<= 1)
                #pragma unroll
                for (int j = 0; j < 3; ++j)
                    part[j] = fmaxf(part[j], __shfl_xor(part[j], off));
            if (xq == 0 && rg < 3) {
                int n = b * C_ + 2 * w + cc;
                float* op = out + (size_t)(n * F_ + f0 + p) * 9 + rg * 3;
                op[0] = part[0]; op[1] = part[1]; op[2] = part[2];
            }
        }

        if (p + 1 < FPB) WRLDS((p + 1) & 1);  // waits its own vmcnt, then writes
        __syncthreads();                       // publish plane p+1; reads of p done
    }
    #undef ISSUE
    #undef WRLDS
}

extern "C" void kernel_launch(void* const* d_in, const int* in_sizes, int n_in,
                              void* d_out, int out_size, void* d_ws, size_t ws_size,
                              hipStream_t stream) {
    const float* feat = (const float*)d_in[0];
    const int*   mask = (const int*)d_in[1];
    int* bb = (int*)d_ws;
    unsigned long long* rowbits = (unsigned long long*)((char*)d_ws + 8192);

    bbox_kernel<<<N_, 256, 0, stream>>>((const int4*)mask, bb, rowbits);
    pool_kernel<<<N_ * 2, 512, 0, stream>>>(feat, rowbits, bb, (float*)d_out);
}

// Round 6
// 169.119 us; speedup vs baseline: 1.2486x; 1.2486x over previous
//
#include <hip/hip_runtime.h>
#include <float.h>

#define B_  8
#define C_  16
#define N_  (B_*C_)
#define F_  256
#define H_  112
#define W_  112
#define HW_ (H_*W_)
#define NB_ 3

#define RB_STRIDE 40      // rowbits stride per cell (ulongs); bh <= 37
#define NPACK 14          // packed bin rows: max bin len = 13 (szy=35 -> bin1 = 24-11),
                          // +1 headroom. Clamped duplicates idempotent under max (proven r3/r4).
#define FSTRIP 8          // features per wave (serial f-loop, prologue amortized 8x)

// ws layout: bb[N_][16] ints at offset 0 (8 KB), rowbits[N_][RB_STRIDE] ulong at +8192.
// bb per cell: y0,y1,x0,x1, ys[3], ye[3], xs[3], xe[3]

__global__ __launch_bounds__(256) void bbox_kernel(const int4* __restrict__ mask4,
                                                   int* __restrict__ bb,
                                                   unsigned long long* __restrict__ rowbits) {
    int n = blockIdx.x, t = threadIdx.x;
    const int4* m = mask4 + (size_t)n * (HW_ / 4);
    int ymin = 1 << 20, ymax = -1, xmin = 1 << 20, xmax = -1;
    // W_/4 = 28 int4 per row; an int4 never straddles rows.
    for (int i = t; i < HW_ / 4; i += 256) {
        int4 v = m[i];
        int y = i / 28;
        int xb = (i - y * 28) * 4;
        if (v.x | v.y | v.z | v.w) { ymin = min(ymin, y); ymax = max(ymax, y); }
        if (v.x) { xmin = min(xmin, xb);     xmax = max(xmax, xb);     }
        if (v.y) { xmin = min(xmin, xb + 1); xmax = max(xmax, xb + 1); }
        if (v.z) { xmin = min(xmin, xb + 2); xmax = max(xmax, xb + 2); }
        if (v.w) { xmin = min(xmin, xb + 3); xmax = max(xmax, xb + 3); }
    }
    #pragma unroll
    for (int off = 32; off; off >>= 1) {
        ymin = min(ymin, __shfl_xor(ymin, off));
        ymax = max(ymax, __shfl_xor(ymax, off));
        xmin = min(xmin, __shfl_xor(xmin, off));
        xmax = max(xmax, __shfl_xor(xmax, off));
    }
    __shared__ int red[4][4];
    __shared__ int sb[3];                 // y0, bh, x0a for phase 2
    int wave = t >> 6;
    if ((t & 63) == 0) {
        red[wave][0] = ymin; red[wave][1] = ymax;
        red[wave][2] = xmin; red[wave][3] = xmax;
    }
    __syncthreads();
    if (t == 0) {
        for (int w = 1; w < 4; ++w) {
            ymin = min(ymin, red[w][0]); ymax = max(ymax, red[w][1]);
            xmin = min(xmin, red[w][2]); xmax = max(xmax, red[w][3]);
        }
        int y0 = ymin, y1 = ymax + 1, x0 = xmin, x1 = xmax + 1;
        int* o = bb + n * 16;
        o[0] = y0; o[1] = y1; o[2] = x0; o[3] = x1;
        int szy = y1 - y0, szx = x1 - x0;
        for (int i = 0; i < NB_; ++i) {
            o[4+i]  = y0 + (i*szy)/NB_;
            o[7+i]  = y0 + ((i+1)*szy + NB_-1)/NB_;
            o[10+i] = x0 + (i*szx)/NB_;
            o[13+i] = x0 + ((i+1)*szx + NB_-1)/NB_;
        }
        sb[0] = y0; sb[1] = szy; sb[2] = x0 & ~3;
    }
    __syncthreads();
    // Phase 2: one 64-bit bitmap per bbox row via ballot. Bit l = mask at col x0a+l.
    // Cols >= W wrap into the next row of the SAME cell; garbage bits sit at
    // cols >= W > x1 and are excluded by the pool epilogue's x-bin lim.
    {
        int y0 = sb[0], bh = sb[1], x0a = sb[2];
        int lane = t & 63;
        const int* mrow = (const int*)mask4 + (size_t)n * HW_ + x0a + lane;
        for (int dy = wave; dy < bh; dy += 4) {
            int v = mrow[(size_t)(y0 + dy) * W_];
            unsigned long long bits = __ballot(v != 0);
            if (lane == 0) rowbits[n * RB_STRIDE + dy] = bits;
        }
    }
}

// PERSISTENT-STRIP pool: grid 1024 x 256 = 4096 waves, one generation resident
// (4 blocks/CU, 16 waves/CU at VGPR<=128). Each wave owns (cell n, 8-feature
// strip): the dependent prologue chain (bb -> rowbits -> mynib -> lims) runs
// ONCE per wave, then 8 independent f-iterations of the proven r4 body (14
// clamped-row float4 loads in flight -> fmax -> epilogue lim + 16-lane shuffle
// reduce -> 9-float store). No barriers, no LDS, no block churn; every wave does
// exactly 14 rows x 8 features -> uniform makespan. Lane map: xq = lane&15 ->
// float4 column group; rg = lane>>4 -> y-bin (bi=min(rg,2); rg3 duplicates bin2:
// idempotent under max).
__global__ __launch_bounds__(256, 4) void pool_kernel(
        const float* __restrict__ feat,
        const unsigned long long* __restrict__ rowbits,
        const int* __restrict__ bb, float* __restrict__ out) {
    int tid  = threadIdx.x;
    int lane = tid & 63, w = tid >> 6;
    int gw = blockIdx.x * 4 + w;          // 0..4095
    int n  = gw >> 5;                     // cell (32 waves per cell)
    int f0 = (gw & 31) * FSTRIP;          // this wave's feature strip
    int b  = n >> 4;                      // batch

    const int* o = bb + n * 16;
    int y0 = o[0], x0 = o[2];
    int bw = o[3] - x0;
    int x0a = x0 & ~3;
    int wbw = (x0 - x0a) + bw;            // aligned working width <= ~38

    int xq = lane & 15, rg = lane >> 4;
    int bi = min(rg, 2);
    int xq4 = (4 * xq < wbw) ? 4 * xq : 0;   // clamp far lanes; epilogue-excluded
    const float* gp = feat + (size_t)(b * F_ + f0) * HW_ + (size_t)y0 * W_ + x0a + xq4;

    int ysb  = o[4 + bi];
    int yeb1 = o[7 + bi] - 1;

    // Row offsets (static unroll -> registers), clamped into the bin.
    int roff[NPACK];
    #pragma unroll
    for (int u = 0; u < NPACK; ++u)
        roff[u] = (min(ysb + u, yeb1) - y0) * W_;

    // Pack this lane's 4 mask bits for rows ysb..ysb+NPACK-1 (clamped) into mynib.
    unsigned long long mynib = 0;
    {
        const unsigned long long* rbp = rowbits + n * RB_STRIDE;
        #pragma unroll
        for (int u = 0; u < NPACK; ++u) {
            int dy = min(ysb + u, yeb1) - y0;
            mynib |= ((rbp[dy] >> (4 * xq)) & 0xFull) << (4 * u);
        }
    }

    // x-bin limits (f-independent): computed once per wave.
    int xg = x0a + 4 * xq;                // UNclamped: far lanes excluded everywhere
    float lim[3][4];
    #pragma unroll
    for (int j = 0; j < 3; ++j) {
        int xs = o[10 + j], xe = o[13 + j];
        #pragma unroll
        for (int s = 0; s < 4; ++s) {
            int xx = xg + s;
            lim[j][s] = (xx >= xs && xx < xe) ? FLT_MAX : -FLT_MAX;
        }
    }

    for (int ff = 0; ff < FSTRIP; ++ff) {
        // Issue ALL row loads (independent, static indices -> registers).
        float4 cr[NPACK];
        #pragma unroll
        for (int u = 0; u < NPACK; ++u)
            cr[u] = *(const float4*)(gp + roff[u]);

        float a0 = -FLT_MAX, a1 = -FLT_MAX, a2 = -FLT_MAX, a3 = -FLT_MAX;
        #pragma unroll
        for (int u = 0; u < NPACK; ++u) {
            unsigned int nib = (unsigned int)(mynib >> (4 * u)) & 0xFu;
            a0 = fmaxf(a0, (nib & 1u) ? cr[u].x : 0.f);
            a1 = fmaxf(a1, (nib & 2u) ? cr[u].y : 0.f);
            a2 = fmaxf(a2, (nib & 4u) ? cr[u].z : 0.f);
            a3 = fmaxf(a3, (nib & 8u) ? cr[u].w : 0.f);
        }

        float part[3];
        #pragma unroll
        for (int j = 0; j < 3; ++j) {
            float r;
            r = fminf(a0, lim[j][0]);
            r = fmaxf(r, fminf(a1, lim[j][1]));
            r = fmaxf(r, fminf(a2, lim[j][2]));
            r = fmaxf(r, fminf(a3, lim[j][3]));
            part[j] = r;
        }
        // reduce within the 16-lane rg-group
        #pragma unroll
        for (int off = 1; off <= 8; off <<= 1) {
            #pragma unroll
            for (int j = 0; j < 3; ++j)
                part[j] = fmaxf(part[j], __shfl_xor(part[j], off));
        }
        if (xq == 0 && rg < 3) {
            float* op = out + (size_t)(n * F_ + f0 + ff) * 9 + rg * 3;
            op[0] = part[0]; op[1] = part[1]; op[2] = part[2];
        }
        gp += HW_;                        // next feature plane
    }
}

extern "C" void kernel_launch(void* const* d_in, const int* in_sizes, int n_in,
                              void* d_out, int out_size, void* d_ws, size_t ws_size,
                              hipStream_t stream) {
    const float* feat = (const float*)d_in[0];
    const int*   mask = (const int*)d_in[1];
    int* bb = (int*)d_ws;
    unsigned long long* rowbits = (unsigned long long*)((char*)d_ws + 8192);

    bbox_kernel<<<N_, 256, 0, stream>>>((const int4*)mask, bb, rowbits);
    pool_kernel<<<1024, 256, 0, stream>>>(feat, rowbits, bb, (float*)d_out);
}